// Round 7
// baseline (145.171 us; speedup 1.0000x reference)
//
#include <hip/hip_runtime.h>
#include <hip/hip_bf16.h>
#include <math.h>

#define NQ 196
#define BATCH 4
#define HD 512            // H * D_K == D_MODEL
#define NH 8
#define DK 64
#define MROWS 784         // BATCH*NQ
#define MPAD 832          // bf16 ws arrays row slack (tile overhang reads)

typedef __attribute__((ext_vector_type(8))) short short8;
typedef __attribute__((ext_vector_type(4))) short short4v;
typedef __attribute__((ext_vector_type(4))) float float4v;

__device__ __forceinline__ float b2f(short s) {
  return __uint_as_float(((unsigned)(unsigned short)s) << 16);
}
__device__ __forceinline__ short f2b(float x) {
  return __builtin_bit_cast(short, __float2bfloat16(x));
}
__device__ __forceinline__ float fexp2(float x) {
  float r; asm("v_exp_f32 %0, %1" : "=v"(r) : "v"(x)); return r;
}
__device__ __forceinline__ float frcp(float x) {
  float r; asm("v_rcp_f32 %0, %1" : "=v"(r) : "v"(x)); return r;
}
__device__ __forceinline__ void cvt4(float4 v, short4v& hi, short4v& lo) {
  float x[4] = {v.x, v.y, v.z, v.w};
  #pragma unroll
  for (int i = 0; i < 4; ++i) {
    hi[i] = f2b(x[i]);
    lo[i] = f2b(x[i] - b2f(hi[i]));
  }
}
// async global->LDS, 16B per lane; LDS dest = wave-uniform base + lane*16
__device__ __forceinline__ void gload_lds16(const void* g, void* l) {
  __builtin_amdgcn_global_load_lds(
      (const __attribute__((address_space(1))) unsigned int*)g,
      (__attribute__((address_space(3))) unsigned int*)l, 16, 0, 0);
}

// ---------------- weight split: fp32 -> bf16 hi/lo (4 matrices) ----------------
struct WSplitArgs { const float* src[4]; short* hi[4]; short* lo[4]; };

__global__ __launch_bounds__(256)
void wsplit_kernel(WSplitArgs a) {
  const int seg = blockIdx.x >> 7;              // 4 segs x 128 blocks
  const size_t off = (size_t)(blockIdx.x & 127) * 2048 + (size_t)threadIdx.x * 8;
  const float* src = a.src[seg] + off;
  float4 v0 = *(const float4*)(src);
  float4 v1 = *(const float4*)(src + 4);
  short4v h0, l0, h1, l1;
  cvt4(v0, h0, l0); cvt4(v1, h1, l1);
  short8 vh = {h0[0],h0[1],h0[2],h0[3],h1[0],h1[1],h1[2],h1[3]};
  short8 vl = {l0[0],l0[1],l0[2],l0[3],l1[0],l1[1],l1[2],l1[3]};
  *(short8*)(a.hi[seg] + off) = vh;
  *(short8*)(a.lo[seg] + off) = vl;
}

// ======== k-split-2 bf16x3 MFMA GEMM core (proj + out variants) ========
// Tile 32(M)x64(N), 512 thr = 2 k-groups x 4 waves, BK=32 per group.
// A fp32 (cvt on the fly), B pre-split bf16 via global_load_lds.
// LDS: A[g][buf][hl][32*32] 16KB + B[g][buf][hl][64*32] 32KB = 48KB; redC aliases A.

struct ProjArgs {
  const float* X[3]; const short* Wh[3]; const short* Wl[3]; const float* bias[3];
  float* Cf[3]; short* Ch[3]; short* Cl[3];
};

__global__ __launch_bounds__(512)
void proj_gemm(ProjArgs p, int M, int N, int K) {
  const int z = blockIdx.z;
  const float* __restrict__ X  = p.X[z];
  const short* __restrict__ Wh = p.Wh[z];
  const short* __restrict__ Wl = p.Wl[z];

  __shared__ short smem[24576];                 // 48 KB
  short* const A_ = smem;                       // [g*2+buf][hl] 1024 each
  short* const B_ = smem + 8192;                // [g*2+buf][hl] 2048 each
  float* const redC = (float*)smem;             // 8KB, aliases A after final barrier

  const int t = threadIdx.x;
  const int g = t >> 8;                         // k-split group
  const int tt = t & 255;
  const int ln = t & 63, lm = ln & 15, quad = ln >> 4;
  const int w = (t >> 6) & 3;                   // wave within group
  const int m0 = blockIdx.x * 32, n0 = blockIdx.y * 64;
  const int kb = g << 8;                        // k base (0 or 256)

  // A staging: 32 rows x 32 k fp32, float4/thread
  const int aRow = tt >> 3, aK = (tt & 7) << 2;
  const int ar = min(m0 + aRow, M - 1);
  const float* Ap = X + (size_t)ar * K + kb + aK;
  const int aIdx = aRow * 32 + aK;
  // B staging: 64 rows x 32 k shorts, 8/thread via DMA (lane-linear tt*8)
  const int bRow = tt >> 2, bK = (tt & 3) << 3;
  const short* Bph = Wh + (size_t)(n0 + bRow) * K + kb + bK;
  const short* Bpl = Wl + (size_t)(n0 + bRow) * K + kb + bK;

  const int wm = (w & 1) << 4, wn = (w >> 1) << 5;
  float4v acc[2] = {{0.f,0.f,0.f,0.f},{0.f,0.f,0.f,0.f}};

  const int T = 8;   // 256/32
  // prologue: buf0
  float4 ra = *(const float4*)Ap;
  gload_lds16(Bph, &B_[((g << 1) + 0) * 4096 + 0 * 2048 + tt * 8]);
  gload_lds16(Bpl, &B_[((g << 1) + 0) * 4096 + 1 * 2048 + tt * 8]);
  {
    short4v ahi, alo; cvt4(ra, ahi, alo);
    *(short4v*)&A_[((g << 1) + 0) * 2048 + 0 * 1024 + aIdx] = ahi;
    *(short4v*)&A_[((g << 1) + 0) * 2048 + 1 * 1024 + aIdx] = alo;
  }

  for (int kt = 0; kt < T; ++kt) {
    const int buf = kt & 1;
    __syncthreads();                            // buf ready (DMA drained here)
    if (kt + 1 < T) {
      ra = *(const float4*)(Ap + (size_t)(kt + 1) * 32);        // issue first
      const int nb = buf ^ 1;
      gload_lds16(Bph + (size_t)(kt + 1) * 32, &B_[((g << 1) + nb) * 4096 + 0 * 2048 + tt * 8]);
      gload_lds16(Bpl + (size_t)(kt + 1) * 32, &B_[((g << 1) + nb) * 4096 + 1 * 2048 + tt * 8]);
    }
    const short* Ab = &A_[((g << 1) + buf) * 2048];
    const short* Bb = &B_[((g << 1) + buf) * 4096];
    short8 fah = *(const short8*)&Ab[0 * 1024 + (wm + lm) * 32 + (quad << 3)];
    short8 fal = *(const short8*)&Ab[1 * 1024 + (wm + lm) * 32 + (quad << 3)];
    #pragma unroll
    for (int ni = 0; ni < 2; ++ni) {
      short8 fbh = *(const short8*)&Bb[0 * 2048 + (wn + (ni << 4) + lm) * 32 + (quad << 3)];
      short8 fbl = *(const short8*)&Bb[1 * 2048 + (wn + (ni << 4) + lm) * 32 + (quad << 3)];
      acc[ni] = __builtin_amdgcn_mfma_f32_16x16x32_bf16(fah, fbh, acc[ni], 0,0,0);
      acc[ni] = __builtin_amdgcn_mfma_f32_16x16x32_bf16(fah, fbl, acc[ni], 0,0,0);
      acc[ni] = __builtin_amdgcn_mfma_f32_16x16x32_bf16(fal, fbh, acc[ni], 0,0,0);
    }
    if (kt + 1 < T) {
      const int nb = buf ^ 1;
      short4v ahi, alo; cvt4(ra, ahi, alo);
      *(short4v*)&A_[((g << 1) + nb) * 2048 + 0 * 1024 + aIdx] = ahi;
      *(short4v*)&A_[((g << 1) + nb) * 2048 + 1 * 1024 + aIdx] = alo;
    }
  }

  __syncthreads();
  if (g == 1) {
    #pragma unroll
    for (int ni = 0; ni < 2; ++ni)
      *(float4v*)&redC[tt * 8 + ni * 4] = acc[ni];
  }
  __syncthreads();
  if (g == 0) {
    const float* bias = p.bias[z];
    float* Cf = p.Cf[z]; short* Ch = p.Ch[z]; short* Cl = p.Cl[z];
    #pragma unroll
    for (int ni = 0; ni < 2; ++ni) {
      const int n = n0 + wn + (ni << 4) + lm;
      const float bv = bias[n];
      #pragma unroll
      for (int r = 0; r < 4; ++r) {
        const int m = m0 + wm + (quad << 2) + r;
        if (m < M) {
          const float c = acc[ni][r] + redC[tt * 8 + ni * 4 + r] + bv;
          if (Cf) Cf[(size_t)m * N + n] = c;
          if (Ch) {
            const short hi = f2b(c);
            Ch[(size_t)m * N + n] = hi;
            Cl[(size_t)m * N + n] = f2b(c - b2f(hi));
          }
        }
      }
    }
  }
}

// out GEMM: A = sum of 4 partial streams; gated epilogue
__global__ __launch_bounds__(512)
void out_gemm(const float* __restrict__ part, const short* __restrict__ Wh,
              const short* __restrict__ Wl, const float* __restrict__ bias,
              const float* __restrict__ qsg, float* __restrict__ C,
              int M, int N, int K) {
  __shared__ short smem[24576];
  short* const A_ = smem;
  short* const B_ = smem + 8192;
  float* const redC = (float*)smem;

  const int t = threadIdx.x;
  const int g = t >> 8;
  const int tt = t & 255;
  const int ln = t & 63, lm = ln & 15, quad = ln >> 4;
  const int w = (t >> 6) & 3;
  const int m0 = blockIdx.x * 32, n0 = blockIdx.y * 64;
  const int kb = g << 8;
  const size_t NELF = (size_t)MROWS * HD;

  const int aRow = tt >> 3, aK = (tt & 7) << 2;
  const int ar = min(m0 + aRow, M - 1);
  const float* Ap = part + (size_t)ar * K + kb + aK;
  const int aIdx = aRow * 32 + aK;
  const int bRow = tt >> 2, bK = (tt & 3) << 3;
  const short* Bph = Wh + (size_t)(n0 + bRow) * K + kb + bK;
  const short* Bpl = Wl + (size_t)(n0 + bRow) * K + kb + bK;

  const int wm = (w & 1) << 4, wn = (w >> 1) << 5;
  float4v acc[2] = {{0.f,0.f,0.f,0.f},{0.f,0.f,0.f,0.f}};

  const int T = 8;
  float4 s0 = *(const float4*)(Ap);
  float4 s1 = *(const float4*)(Ap + NELF);
  float4 s2 = *(const float4*)(Ap + 2 * NELF);
  float4 s3 = *(const float4*)(Ap + 3 * NELF);
  gload_lds16(Bph, &B_[((g << 1) + 0) * 4096 + 0 * 2048 + tt * 8]);
  gload_lds16(Bpl, &B_[((g << 1) + 0) * 4096 + 1 * 2048 + tt * 8]);
  {
    float4 ra = make_float4(s0.x+s1.x+s2.x+s3.x, s0.y+s1.y+s2.y+s3.y,
                            s0.z+s1.z+s2.z+s3.z, s0.w+s1.w+s2.w+s3.w);
    short4v ahi, alo; cvt4(ra, ahi, alo);
    *(short4v*)&A_[((g << 1) + 0) * 2048 + 0 * 1024 + aIdx] = ahi;
    *(short4v*)&A_[((g << 1) + 0) * 2048 + 1 * 1024 + aIdx] = alo;
  }

  for (int kt = 0; kt < T; ++kt) {
    const int buf = kt & 1;
    __syncthreads();
    if (kt + 1 < T) {
      const size_t ko = (size_t)(kt + 1) * 32;
      s0 = *(const float4*)(Ap + ko);
      s1 = *(const float4*)(Ap + NELF + ko);
      s2 = *(const float4*)(Ap + 2 * NELF + ko);
      s3 = *(const float4*)(Ap + 3 * NELF + ko);
      const int nb = buf ^ 1;
      gload_lds16(Bph + ko, &B_[((g << 1) + nb) * 4096 + 0 * 2048 + tt * 8]);
      gload_lds16(Bpl + ko, &B_[((g << 1) + nb) * 4096 + 1 * 2048 + tt * 8]);
    }
    const short* Ab = &A_[((g << 1) + buf) * 2048];
    const short* Bb = &B_[((g << 1) + buf) * 4096];
    short8 fah = *(const short8*)&Ab[0 * 1024 + (wm + lm) * 32 + (quad << 3)];
    short8 fal = *(const short8*)&Ab[1 * 1024 + (wm + lm) * 32 + (quad << 3)];
    #pragma unroll
    for (int ni = 0; ni < 2; ++ni) {
      short8 fbh = *(const short8*)&Bb[0 * 2048 + (wn + (ni << 4) + lm) * 32 + (quad << 3)];
      short8 fbl = *(const short8*)&Bb[1 * 2048 + (wn + (ni << 4) + lm) * 32 + (quad << 3)];
      acc[ni] = __builtin_amdgcn_mfma_f32_16x16x32_bf16(fah, fbh, acc[ni], 0,0,0);
      acc[ni] = __builtin_amdgcn_mfma_f32_16x16x32_bf16(fah, fbl, acc[ni], 0,0,0);
      acc[ni] = __builtin_amdgcn_mfma_f32_16x16x32_bf16(fal, fbh, acc[ni], 0,0,0);
    }
    if (kt + 1 < T) {
      const int nb = buf ^ 1;
      float4 ra = make_float4(s0.x+s1.x+s2.x+s3.x, s0.y+s1.y+s2.y+s3.y,
                              s0.z+s1.z+s2.z+s3.z, s0.w+s1.w+s2.w+s3.w);
      short4v ahi, alo; cvt4(ra, ahi, alo);
      *(short4v*)&A_[((g << 1) + nb) * 2048 + 0 * 1024 + aIdx] = ahi;
      *(short4v*)&A_[((g << 1) + nb) * 2048 + 1 * 1024 + aIdx] = alo;
    }
  }

  __syncthreads();
  if (g == 1) {
    #pragma unroll
    for (int ni = 0; ni < 2; ++ni)
      *(float4v*)&redC[tt * 8 + ni * 4] = acc[ni];
  }
  __syncthreads();
  if (g == 0) {
    #pragma unroll
    for (int ni = 0; ni < 2; ++ni) {
      const int n = n0 + wn + (ni << 4) + lm;
      const float bv = bias[n];
      #pragma unroll
      for (int r = 0; r < 4; ++r) {
        const int m = m0 + wm + (quad << 2) + r;
        if (m < M) {
          float c = acc[ni][r] + redC[tt * 8 + ni * 4 + r] + bv;
          const float qg = qsg[(size_t)m * N + n];
          c = __fdividef(c, 1.f + __expf(-qg * c));   // sigmoid(qg*c)*c
          C[(size_t)m * N + n] = c;
        }
      }
    }
  }
}

// -------- fused scores (MFMA) + softmax -> p, S never leaves LDS --------
__global__ __launch_bounds__(256)
void scores_softmax(const short* __restrict__ qsh, const short* __restrict__ qsl,
                    const short* __restrict__ ksh, const short* __restrict__ ksl,
                    const float* __restrict__ scg, float* __restrict__ pbuf) {
  const int q0 = blockIdx.x * 16;
  const int bh = blockIdx.y;
  const int b = bh >> 3, h = bh & 7;
  const int w = threadIdx.x >> 6, ln = threadIdx.x & 63;
  const int lm = ln & 15, quad = ln >> 4;
  const float L2E = 1.4426950408889634f;

  __shared__ float S[16][210];

  const size_t abase = ((size_t)(b * NQ) + q0 + lm) * HD + h * DK + (quad << 3);
  short8 ah0 = *(const short8*)(qsh + abase);
  short8 ah1 = *(const short8*)(qsh + abase + 32);
  short8 al0 = *(const short8*)(qsl + abase);
  short8 al1 = *(const short8*)(qsl + abase + 32);

  for (int nt = w; nt < 13; nt += 4) {
    const size_t bbase = ((size_t)(b * NQ) + nt * 16 + lm) * HD + h * DK + (quad << 3);
    short8 bh0 = *(const short8*)(ksh + bbase);
    short8 bh1 = *(const short8*)(ksh + bbase + 32);
    short8 bl0 = *(const short8*)(ksl + bbase);
    short8 bl1 = *(const short8*)(ksl + bbase + 32);
    float4v acc = {0.f, 0.f, 0.f, 0.f};
    acc = __builtin_amdgcn_mfma_f32_16x16x32_bf16(ah0, bh0, acc, 0,0,0);
    acc = __builtin_amdgcn_mfma_f32_16x16x32_bf16(ah1, bh1, acc, 0,0,0);
    acc = __builtin_amdgcn_mfma_f32_16x16x32_bf16(ah0, bl0, acc, 0,0,0);
    acc = __builtin_amdgcn_mfma_f32_16x16x32_bf16(ah1, bl1, acc, 0,0,0);
    acc = __builtin_amdgcn_mfma_f32_16x16x32_bf16(al0, bh0, acc, 0,0,0);
    acc = __builtin_amdgcn_mfma_f32_16x16x32_bf16(al1, bh1, acc, 0,0,0);
    #pragma unroll
    for (int r = 0; r < 4; ++r)
      S[(quad << 2) + r][nt * 16 + lm] = acc[r];
  }
  __syncthreads();

  for (int i = 0; i < 4; ++i) {
    const int rr = (w << 2) + i;
    const int q = q0 + rr;
    const bool qok = q < NQ;
    const float* srow = scg + ((size_t)h * NQ + (qok ? q : 0)) * NQ;
    float att[4];
    #pragma unroll
    for (int j = 0; j < 4; ++j) {
      const int c = ln + (j << 6);
      att[j] = -1e30f;
      if (c < NQ) att[j] = S[rr][c] * srow[c] * L2E;
    }
    float m = fmaxf(fmaxf(att[0], att[1]), fmaxf(att[2], att[3]));
    #pragma unroll
    for (int off = 32; off; off >>= 1) m = fmaxf(m, __shfl_xor(m, off, 64));
    float e[4], s = 0.f;
    #pragma unroll
    for (int j = 0; j < 4; ++j) { e[j] = fexp2(att[j] - m); s += e[j]; }
    #pragma unroll
    for (int off = 32; off; off >>= 1) s += __shfl_xor(s, off, 64);
    const float rinv = __fdividef(1.f, s);
    if (qok) {
      float* prow = pbuf + (((size_t)(b * NH + h) * NQ) + q) * NQ;
      #pragma unroll
      for (int j = 0; j < 4; ++j) {
        const int c = ln + (j << 6);
        if (c < NQ) prow[c] = e[j] * rinv;
      }
    }
  }
}

// ---------------- gated PV: QB=4, k-split 4, 256-thr blocks ----------------
__global__ __launch_bounds__(256)
void pv_kernel(const float* __restrict__ qsg, const float* __restrict__ kpg,
               const float* __restrict__ vpg, const float* __restrict__ pbuf,
               float* __restrict__ part) {
  const int b  = blockIdx.y;
  const int x  = blockIdx.x;        // 49 q-groups x 4 ks x 2 d-halves = 392
  const int qg = x >> 3;
  const int ks = (x >> 1) & 3;
  const int dh = x & 1;
  const int q0 = qg << 2;
  const int hd = (dh << 8) + threadIdx.x;
  const int h  = hd >> 6;
  const float LOG2E = 1.4426950408889634f;

  const size_t r0 = ((size_t)(b * NQ) + q0) * HD + hd;
  float nqs[4];
  #pragma unroll
  for (int qi = 0; qi < 4; ++qi)
    nqs[qi] = -qsg[r0 + (size_t)qi * HD] * LOG2E;

  const float* kp = kpg + (size_t)b * NQ * HD + hd;
  const float* vp = vpg + (size_t)b * NQ * HD + hd;
  const float* pr = pbuf + ((size_t)(b * NH + h) * NQ + q0) * NQ;

  float acc[4] = {0.f, 0.f, 0.f, 0.f};
  const int kbeg = ks * 49;
  for (int k = kbeg; k < kbeg + 49; ++k) {
    const float kv = kp[(size_t)k * HD];
    const float vv = vp[(size_t)k * HD];
    #pragma unroll
    for (int qi = 0; qi < 4; ++qi) {
      const float e = fexp2(nqs[qi] * kv);          // e^(-qs*kv)
      const float g = vv * frcp(1.f + e);           // sigmoid(qs*kv)*vv
      acc[qi] += pr[(size_t)qi * NQ + k] * g;
    }
  }
  float* dst = part + (size_t)ks * ((size_t)MROWS * HD) + r0;
  #pragma unroll
  for (int qi = 0; qi < 4; ++qi) dst[(size_t)qi * HD] = acc[qi];
}

extern "C" void kernel_launch(void* const* d_in, const int* in_sizes, int n_in,
                              void* d_out, int out_size, void* d_ws, size_t ws_size,
                              hipStream_t stream) {
  const float* queries = (const float*)d_in[0];
  const float* keys    = (const float*)d_in[1];
  const float* values  = (const float*)d_in[2];
  const float* Wq = (const float*)d_in[3];
  const float* bq = (const float*)d_in[4];
  const float* Wk = (const float*)d_in[5];
  const float* bk = (const float*)d_in[6];
  const float* Wv = (const float*)d_in[7];
  const float* bv = (const float*)d_in[8];
  const float* Wo = (const float*)d_in[9];
  const float* bo = (const float*)d_in[10];
  const float* scale = (const float*)d_in[11];

  char* base = (char*)d_ws;
  const size_t FB = sizeof(float);
  const size_t NELF  = (size_t)MROWS * HD;   // 401408
  const size_t NELPS = (size_t)MPAD * HD;    // 425984
  const size_t WEL   = (size_t)HD * HD;      // 262144

  size_t o = 0;
  float* q_sig = (float*)(base + o); o += NELF * FB;
  float* k_p   = (float*)(base + o); o += NELF * FB;
  float* v_p   = (float*)(base + o); o += NELF * FB;
  float* pbuf  = (float*)(base + o); o += (size_t)BATCH * NH * NQ * NQ * FB;
  short* qsh = (short*)(base + o); o += NELPS * 2;
  short* qsl = (short*)(base + o); o += NELPS * 2;
  short* ksh = (short*)(base + o); o += NELPS * 2;
  short* ksl = (short*)(base + o); o += NELPS * 2;
  short* Wqh = (short*)(base + o); o += WEL * 2;
  short* Wql = (short*)(base + o); o += WEL * 2;
  short* Wkh = (short*)(base + o); o += WEL * 2;
  short* Wkl = (short*)(base + o); o += WEL * 2;
  short* Wvh = (short*)(base + o); o += WEL * 2;
  short* Wvl = (short*)(base + o); o += WEL * 2;
  short* Woh = (short*)(base + o); o += WEL * 2;
  short* Wol = (short*)(base + o); o += WEL * 2;
  float* part = (float*)(base + o); o += 4 * NELF * FB;

  // 0) split weights once
  WSplitArgs wa;
  wa.src[0] = Wq; wa.hi[0] = Wqh; wa.lo[0] = Wql;
  wa.src[1] = Wk; wa.hi[1] = Wkh; wa.lo[1] = Wkl;
  wa.src[2] = Wv; wa.hi[2] = Wvh; wa.lo[2] = Wvl;
  wa.src[3] = Wo; wa.hi[3] = Woh; wa.lo[3] = Wol;
  wsplit_kernel<<<512, 256, 0, stream>>>(wa);

  // 1) projections: z0 q_sig (fp32 + split), z1 k_p (fp32 + split), z2 v_p (fp32)
  ProjArgs gp;
  gp.X[0] = queries; gp.Wh[0] = Wqh; gp.Wl[0] = Wql; gp.bias[0] = bq;
  gp.Cf[0] = q_sig;  gp.Ch[0] = qsh; gp.Cl[0] = qsl;
  gp.X[1] = keys;    gp.Wh[1] = Wkh; gp.Wl[1] = Wkl; gp.bias[1] = bk;
  gp.Cf[1] = k_p;    gp.Ch[1] = ksh; gp.Cl[1] = ksl;
  gp.X[2] = values;  gp.Wh[2] = Wvh; gp.Wl[2] = Wvl; gp.bias[2] = bv;
  gp.Cf[2] = v_p;    gp.Ch[2] = nullptr; gp.Cl[2] = nullptr;
  proj_gemm<<<dim3(25, HD/64, 3), 512, 0, stream>>>(gp, MROWS, HD, HD);

  // 2) fused scores + softmax -> pbuf
  scores_softmax<<<dim3(13, NH*BATCH), 256, 0, stream>>>(qsh, qsl, ksh, ksl, scale, pbuf);

  // 3) gated PV partials (4 k-slices, 2 d-halves)
  pv_kernel<<<dim3(392, BATCH), 256, 0, stream>>>(q_sig, k_p, v_p, pbuf, part);

  // 4) out = (sum partials) @ Wo^T + bo, gated by q_sig
  out_gemm<<<dim3(25, HD/64), 512, 0, stream>>>(part, Woh, Wol, bo, q_sig,
                                                (float*)d_out, MROWS, HD, HD);
}

// Round 8
// 143.101 us; speedup vs baseline: 1.0145x; 1.0145x over previous
//
#include <hip/hip_runtime.h>
#include <hip/hip_bf16.h>
#include <math.h>

#define NQ 196
#define BATCH 4
#define HD 512            // H * D_K == D_MODEL
#define NH 8
#define DK 64
#define MROWS 784         // BATCH*NQ
#define MPAD 832          // bf16 ws arrays row slack (tile overhang reads)

typedef __attribute__((ext_vector_type(8))) short short8;
typedef __attribute__((ext_vector_type(4))) short short4v;
typedef __attribute__((ext_vector_type(4))) float float4v;

__device__ __forceinline__ float b2f(short s) {
  return __uint_as_float(((unsigned)(unsigned short)s) << 16);
}
__device__ __forceinline__ short f2b(float x) {
  return __builtin_bit_cast(short, __float2bfloat16(x));
}
__device__ __forceinline__ float fexp2(float x) {
  float r; asm("v_exp_f32 %0, %1" : "=v"(r) : "v"(x)); return r;
}
__device__ __forceinline__ float frcp(float x) {
  float r; asm("v_rcp_f32 %0, %1" : "=v"(r) : "v"(x)); return r;
}
__device__ __forceinline__ void cvt4(float4 v, short4v& hi, short4v& lo) {
  float x[4] = {v.x, v.y, v.z, v.w};
  #pragma unroll
  for (int i = 0; i < 4; ++i) {
    hi[i] = f2b(x[i]);
    lo[i] = f2b(x[i] - b2f(hi[i]));
  }
}
__device__ __forceinline__ void gload_lds16(const void* g, void* l) {
  __builtin_amdgcn_global_load_lds(
      (const __attribute__((address_space(1))) unsigned int*)g,
      (__attribute__((address_space(3))) unsigned int*)l, 16, 0, 0);
}

// ---------------- weight split: fp32 -> bf16 hi/lo (4 matrices) ----------------
struct WSplitArgs { const float* src[4]; short* hi[4]; short* lo[4]; };

__global__ __launch_bounds__(256)
void wsplit_kernel(WSplitArgs a) {
  const int seg = blockIdx.x >> 7;              // 4 segs x 128 blocks
  const size_t off = (size_t)(blockIdx.x & 127) * 2048 + (size_t)threadIdx.x * 8;
  const float* src = a.src[seg] + off;
  float4 v0 = *(const float4*)(src);
  float4 v1 = *(const float4*)(src + 4);
  short4v h0, l0, h1, l1;
  cvt4(v0, h0, l0); cvt4(v1, h1, l1);
  short8 vh = {h0[0],h0[1],h0[2],h0[3],h1[0],h1[1],h1[2],h1[3]};
  short8 vl = {l0[0],l0[1],l0[2],l0[3],l1[0],l1[1],l1[2],l1[3]};
  *(short8*)(a.hi[seg] + off) = vh;
  *(short8*)(a.lo[seg] + off) = vl;
}

// ======== k-split-2 bf16x3 MFMA GEMM (used for proj and out) ========
// Tile 32(M)x64(N), 512 thr = 2 k-groups x 4 waves, BK=32 per group.
// A fp32 (cvt on the fly), B pre-split bf16 via global_load_lds.
// Optional gate epilogue: c = sigmoid(gate*c)*c.
struct GemmArgs {
  const float* X[3]; const short* Wh[3]; const short* Wl[3]; const float* bias[3];
  float* Cf[3]; short* Ch[3]; short* Cl[3]; const float* gate[3];
};

__global__ __launch_bounds__(512)
void mgemm(GemmArgs p, int M, int N, int K) {
  const int z = blockIdx.z;
  const float* __restrict__ X  = p.X[z];
  const short* __restrict__ Wh = p.Wh[z];
  const short* __restrict__ Wl = p.Wl[z];

  __shared__ short smem[24576];                 // 48 KB
  short* const A_ = smem;
  short* const B_ = smem + 8192;
  float* const redC = (float*)smem;             // aliases A after final barrier

  const int t = threadIdx.x;
  const int g = t >> 8;
  const int tt = t & 255;
  const int ln = t & 63, lm = ln & 15, quad = ln >> 4;
  const int w = (t >> 6) & 3;
  const int m0 = blockIdx.x * 32, n0 = blockIdx.y * 64;
  const int kb = g << 8;

  const int aRow = tt >> 3, aK = (tt & 7) << 2;
  const int ar = min(m0 + aRow, M - 1);
  const float* Ap = X + (size_t)ar * K + kb + aK;
  const int aIdx = aRow * 32 + aK;
  const int bRow = tt >> 2, bK = (tt & 3) << 3;
  const short* Bph = Wh + (size_t)(n0 + bRow) * K + kb + bK;
  const short* Bpl = Wl + (size_t)(n0 + bRow) * K + kb + bK;

  const int wm = (w & 1) << 4, wn = (w >> 1) << 5;
  float4v acc[2] = {{0.f,0.f,0.f,0.f},{0.f,0.f,0.f,0.f}};

  const int T = 8;
  float4 ra = *(const float4*)Ap;
  gload_lds16(Bph, &B_[((g << 1) + 0) * 4096 + 0 * 2048 + tt * 8]);
  gload_lds16(Bpl, &B_[((g << 1) + 0) * 4096 + 1 * 2048 + tt * 8]);
  {
    short4v ahi, alo; cvt4(ra, ahi, alo);
    *(short4v*)&A_[((g << 1) + 0) * 2048 + 0 * 1024 + aIdx] = ahi;
    *(short4v*)&A_[((g << 1) + 0) * 2048 + 1 * 1024 + aIdx] = alo;
  }

  for (int kt = 0; kt < T; ++kt) {
    const int buf = kt & 1;
    __syncthreads();
    if (kt + 1 < T) {
      ra = *(const float4*)(Ap + (size_t)(kt + 1) * 32);
      const int nb = buf ^ 1;
      gload_lds16(Bph + (size_t)(kt + 1) * 32, &B_[((g << 1) + nb) * 4096 + 0 * 2048 + tt * 8]);
      gload_lds16(Bpl + (size_t)(kt + 1) * 32, &B_[((g << 1) + nb) * 4096 + 1 * 2048 + tt * 8]);
    }
    const short* Ab = &A_[((g << 1) + buf) * 2048];
    const short* Bb = &B_[((g << 1) + buf) * 4096];
    short8 fah = *(const short8*)&Ab[0 * 1024 + (wm + lm) * 32 + (quad << 3)];
    short8 fal = *(const short8*)&Ab[1 * 1024 + (wm + lm) * 32 + (quad << 3)];
    #pragma unroll
    for (int ni = 0; ni < 2; ++ni) {
      short8 fbh = *(const short8*)&Bb[0 * 2048 + (wn + (ni << 4) + lm) * 32 + (quad << 3)];
      short8 fbl = *(const short8*)&Bb[1 * 2048 + (wn + (ni << 4) + lm) * 32 + (quad << 3)];
      acc[ni] = __builtin_amdgcn_mfma_f32_16x16x32_bf16(fah, fbh, acc[ni], 0,0,0);
      acc[ni] = __builtin_amdgcn_mfma_f32_16x16x32_bf16(fah, fbl, acc[ni], 0,0,0);
      acc[ni] = __builtin_amdgcn_mfma_f32_16x16x32_bf16(fal, fbh, acc[ni], 0,0,0);
    }
    if (kt + 1 < T) {
      const int nb = buf ^ 1;
      short4v ahi, alo; cvt4(ra, ahi, alo);
      *(short4v*)&A_[((g << 1) + nb) * 2048 + 0 * 1024 + aIdx] = ahi;
      *(short4v*)&A_[((g << 1) + nb) * 2048 + 1 * 1024 + aIdx] = alo;
    }
  }

  __syncthreads();
  if (g == 1) {
    #pragma unroll
    for (int ni = 0; ni < 2; ++ni)
      *(float4v*)&redC[tt * 8 + ni * 4] = acc[ni];
  }
  __syncthreads();
  if (g == 0) {
    const float* bias = p.bias[z];
    const float* gate = p.gate[z];
    float* Cf = p.Cf[z]; short* Ch = p.Ch[z]; short* Cl = p.Cl[z];
    #pragma unroll
    for (int ni = 0; ni < 2; ++ni) {
      const int n = n0 + wn + (ni << 4) + lm;
      const float bv = bias[n];
      #pragma unroll
      for (int r = 0; r < 4; ++r) {
        const int m = m0 + wm + (quad << 2) + r;
        if (m < M) {
          float c = acc[ni][r] + redC[tt * 8 + ni * 4 + r] + bv;
          if (gate) {
            const float qg = gate[(size_t)m * N + n];
            c = __fdividef(c, 1.f + __expf(-qg * c));   // sigmoid(qg*c)*c
          }
          if (Cf) Cf[(size_t)m * N + n] = c;
          if (Ch) {
            const short hi = f2b(c);
            Ch[(size_t)m * N + n] = hi;
            Cl[(size_t)m * N + n] = f2b(c - b2f(hi));
          }
        }
      }
    }
  }
}

// ======== fused attention: scores (MFMA) + softmax + gated PV ========
// One block per (q-tile 16, h, b). S and p never leave LDS.
__global__ __launch_bounds__(256)
void attn_fused(const short* __restrict__ qsh, const short* __restrict__ qsl,
                const short* __restrict__ ksh, const short* __restrict__ ksl,
                const float* __restrict__ qsg, const float* __restrict__ kpg,
                const float* __restrict__ vpg, const float* __restrict__ scg,
                float* __restrict__ img) {
  const int q0 = blockIdx.x * 16;
  const int h  = blockIdx.y;
  const int b  = blockIdx.z;
  const int t  = threadIdx.x;
  const int w = t >> 6, ln = t & 63;
  const int lm = ln & 15, quad = ln >> 4;
  const float L2E = 1.4426950408889634f;

  __shared__ float S[16][210];     // scores, then p (k-broadcast reads are free)
  __shared__ float R[4][16][64];   // pv k-group partials

  // ---- phase 1: S = q_sig . k_p^T (bf16x3 MFMA), per head slice ----
  const size_t abase = ((size_t)(b * NQ) + q0 + lm) * HD + h * DK + (quad << 3);
  short8 ah0 = *(const short8*)(qsh + abase);
  short8 ah1 = *(const short8*)(qsh + abase + 32);
  short8 al0 = *(const short8*)(qsl + abase);
  short8 al1 = *(const short8*)(qsl + abase + 32);

  for (int nt = w; nt < 13; nt += 4) {
    const size_t bbase = ((size_t)(b * NQ) + nt * 16 + lm) * HD + h * DK + (quad << 3);
    short8 bh0 = *(const short8*)(ksh + bbase);
    short8 bh1 = *(const short8*)(ksh + bbase + 32);
    short8 bl0 = *(const short8*)(ksl + bbase);
    short8 bl1 = *(const short8*)(ksl + bbase + 32);
    float4v acc = {0.f, 0.f, 0.f, 0.f};
    acc = __builtin_amdgcn_mfma_f32_16x16x32_bf16(ah0, bh0, acc, 0,0,0);
    acc = __builtin_amdgcn_mfma_f32_16x16x32_bf16(ah1, bh1, acc, 0,0,0);
    acc = __builtin_amdgcn_mfma_f32_16x16x32_bf16(ah0, bl0, acc, 0,0,0);
    acc = __builtin_amdgcn_mfma_f32_16x16x32_bf16(ah1, bl1, acc, 0,0,0);
    acc = __builtin_amdgcn_mfma_f32_16x16x32_bf16(al0, bh0, acc, 0,0,0);
    acc = __builtin_amdgcn_mfma_f32_16x16x32_bf16(al1, bh1, acc, 0,0,0);
    #pragma unroll
    for (int r = 0; r < 4; ++r)
      S[(quad << 2) + r][nt * 16 + lm] = acc[r];
  }
  __syncthreads();

  // ---- phase 2: softmax rows in place (wave w: rows 4w..4w+3) ----
  for (int i = 0; i < 4; ++i) {
    const int rr = (w << 2) + i;
    const int q = q0 + rr;
    const bool qok = q < NQ;
    const float* srow = scg + ((size_t)h * NQ + (qok ? q : 0)) * NQ;
    float att[4];
    #pragma unroll
    for (int j = 0; j < 4; ++j) {
      const int c = ln + (j << 6);
      att[j] = -1e30f;
      if (c < NQ) att[j] = S[rr][c] * srow[c] * L2E;
    }
    float m = fmaxf(fmaxf(att[0], att[1]), fmaxf(att[2], att[3]));
    #pragma unroll
    for (int off = 32; off; off >>= 1) m = fmaxf(m, __shfl_xor(m, off, 64));
    float e[4], s = 0.f;
    #pragma unroll
    for (int j = 0; j < 4; ++j) { e[j] = fexp2(att[j] - m); s += e[j]; }
    #pragma unroll
    for (int off = 32; off; off >>= 1) s += __shfl_xor(s, off, 64);
    const float rinv = __fdividef(1.f, s);
    #pragma unroll
    for (int j = 0; j < 4; ++j) {
      const int c = ln + (j << 6);
      if (c < NQ) S[rr][c] = e[j] * rinv;
    }
  }
  __syncthreads();

  // ---- phase 3: gated PV. thread = (d = t&63, kgroup = t>>6). ----
  const int d = ln;              // 0..63 within head
  const int kg = w;              // 0..3
  const float LOG2E = 1.4426950408889634f;

  float nqs[16];
  #pragma unroll
  for (int qi = 0; qi < 16; ++qi) {
    const int row = min(b * NQ + q0 + qi, MROWS - 1);   // clamp tile overhang
    nqs[qi] = -qsg[(size_t)row * HD + h * DK + d] * LOG2E;
  }
  const float* kp = kpg + ((size_t)(b * NQ)) * HD + h * DK + d;
  const float* vp = vpg + ((size_t)(b * NQ)) * HD + h * DK + d;

  float acc[16];
  #pragma unroll
  for (int qi = 0; qi < 16; ++qi) acc[qi] = 0.f;

  for (int k = kg * 49; k < kg * 49 + 49; ++k) {
    const float kv = kp[(size_t)k * HD];
    const float vv = vp[(size_t)k * HD];
    #pragma unroll
    for (int qi = 0; qi < 16; ++qi) {
      const float e = fexp2(nqs[qi] * kv);          // e^(-qs*kv)
      const float g = vv * frcp(1.f + e);           // sigmoid(qs*kv)*vv
      acc[qi] += S[qi][k] * g;
    }
  }
  #pragma unroll
  for (int qi = 0; qi < 16; ++qi) R[kg][qi][d] = acc[qi];
  __syncthreads();

  #pragma unroll
  for (int j = 0; j < 4; ++j) {
    const int idx = t + (j << 8);
    const int qi = idx >> 6, dd = idx & 63;
    const int q = q0 + qi;
    if (q < NQ) {
      const float s = R[0][qi][dd] + R[1][qi][dd] + R[2][qi][dd] + R[3][qi][dd];
      img[((size_t)(b * NQ) + q) * HD + h * DK + dd] = s;
    }
  }
}

extern "C" void kernel_launch(void* const* d_in, const int* in_sizes, int n_in,
                              void* d_out, int out_size, void* d_ws, size_t ws_size,
                              hipStream_t stream) {
  const float* queries = (const float*)d_in[0];
  const float* keys    = (const float*)d_in[1];
  const float* values  = (const float*)d_in[2];
  const float* Wq = (const float*)d_in[3];
  const float* bq = (const float*)d_in[4];
  const float* Wk = (const float*)d_in[5];
  const float* bk = (const float*)d_in[6];
  const float* Wv = (const float*)d_in[7];
  const float* bv = (const float*)d_in[8];
  const float* Wo = (const float*)d_in[9];
  const float* bo = (const float*)d_in[10];
  const float* scale = (const float*)d_in[11];

  char* base = (char*)d_ws;
  const size_t FB = sizeof(float);
  const size_t NELF  = (size_t)MROWS * HD;   // 401408
  const size_t NELPS = (size_t)MPAD * HD;    // 425984
  const size_t WEL   = (size_t)HD * HD;      // 262144

  size_t o = 0;
  float* q_sig = (float*)(base + o); o += NELF * FB;
  float* k_p   = (float*)(base + o); o += NELF * FB;
  float* v_p   = (float*)(base + o); o += NELF * FB;
  float* image = (float*)(base + o); o += NELF * FB;
  short* qsh = (short*)(base + o); o += NELPS * 2;
  short* qsl = (short*)(base + o); o += NELPS * 2;
  short* ksh = (short*)(base + o); o += NELPS * 2;
  short* ksl = (short*)(base + o); o += NELPS * 2;
  short* Wqh = (short*)(base + o); o += WEL * 2;
  short* Wql = (short*)(base + o); o += WEL * 2;
  short* Wkh = (short*)(base + o); o += WEL * 2;
  short* Wkl = (short*)(base + o); o += WEL * 2;
  short* Wvh = (short*)(base + o); o += WEL * 2;
  short* Wvl = (short*)(base + o); o += WEL * 2;
  short* Woh = (short*)(base + o); o += WEL * 2;
  short* Wol = (short*)(base + o); o += WEL * 2;

  // 0) split weights once
  WSplitArgs wa;
  wa.src[0] = Wq; wa.hi[0] = Wqh; wa.lo[0] = Wql;
  wa.src[1] = Wk; wa.hi[1] = Wkh; wa.lo[1] = Wkl;
  wa.src[2] = Wv; wa.hi[2] = Wvh; wa.lo[2] = Wvl;
  wa.src[3] = Wo; wa.hi[3] = Woh; wa.lo[3] = Wol;
  wsplit_kernel<<<512, 256, 0, stream>>>(wa);

  // 1) projections: z0 q_sig (fp32 + split), z1 k_p (fp32 + split), z2 v_p (fp32)
  GemmArgs gp;
  gp.X[0] = queries; gp.Wh[0] = Wqh; gp.Wl[0] = Wql; gp.bias[0] = bq;
  gp.Cf[0] = q_sig;  gp.Ch[0] = qsh; gp.Cl[0] = qsl; gp.gate[0] = nullptr;
  gp.X[1] = keys;    gp.Wh[1] = Wkh; gp.Wl[1] = Wkl; gp.bias[1] = bk;
  gp.Cf[1] = k_p;    gp.Ch[1] = ksh; gp.Cl[1] = ksl; gp.gate[1] = nullptr;
  gp.X[2] = values;  gp.Wh[2] = Wvh; gp.Wl[2] = Wvl; gp.bias[2] = bv;
  gp.Cf[2] = v_p;    gp.Ch[2] = nullptr; gp.Cl[2] = nullptr; gp.gate[2] = nullptr;
  mgemm<<<dim3(25, HD/64, 3), 512, 0, stream>>>(gp, MROWS, HD, HD);

  // 2) fused scores + softmax + gated PV -> image
  attn_fused<<<dim3(13, NH, BATCH), 256, 0, stream>>>(
      qsh, qsl, ksh, ksl, q_sig, k_p, v_p, scale, image);

  // 3) out = image @ Wo^T + bo, gated by q_sig
  GemmArgs go;
  go.X[0] = image; go.Wh[0] = Woh; go.Wl[0] = Wol; go.bias[0] = bo;
  go.Cf[0] = (float*)d_out; go.Ch[0] = nullptr; go.Cl[0] = nullptr; go.gate[0] = q_sig;
  for (int i = 1; i < 3; ++i) {
    go.X[i] = nullptr; go.Wh[i] = nullptr; go.Wl[i] = nullptr; go.bias[i] = nullptr;
    go.Cf[i] = nullptr; go.Ch[i] = nullptr; go.Cl[i] = nullptr; go.gate[i] = nullptr;
  }
  mgemm<<<dim3(25, HD/64, 1), 512, 0, stream>>>(go, MROWS, HD, HD);
}

// Round 9
// 138.500 us; speedup vs baseline: 1.0482x; 1.0332x over previous
//
#include <hip/hip_runtime.h>
#include <hip/hip_bf16.h>
#include <math.h>

#define NQ 196
#define BATCH 4
#define HD 512            // H * D_K == D_MODEL
#define NH 8
#define DK 64
#define MROWS 784         // BATCH*NQ = 49*16
#define MPAD 832          // bf16 ws arrays row slack (attn tile overhang reads)

typedef __attribute__((ext_vector_type(8))) short short8;
typedef __attribute__((ext_vector_type(4))) short short4v;
typedef __attribute__((ext_vector_type(4))) float float4v;

__device__ __forceinline__ float b2f(short s) {
  return __uint_as_float(((unsigned)(unsigned short)s) << 16);
}
__device__ __forceinline__ short f2b(float x) {
  return __builtin_bit_cast(short, __float2bfloat16(x));
}
__device__ __forceinline__ float fexp2(float x) {
  float r; asm("v_exp_f32 %0, %1" : "=v"(r) : "v"(x)); return r;
}
__device__ __forceinline__ float frcp(float x) {
  float r; asm("v_rcp_f32 %0, %1" : "=v"(r) : "v"(x)); return r;
}
__device__ __forceinline__ void cvt4(float4 v, short4v& hi, short4v& lo) {
  float x[4] = {v.x, v.y, v.z, v.w};
  #pragma unroll
  for (int i = 0; i < 4; ++i) {
    hi[i] = f2b(x[i]);
    lo[i] = f2b(x[i] - b2f(hi[i]));
  }
}
__device__ __forceinline__ void gload_lds16(const void* g, void* l) {
  __builtin_amdgcn_global_load_lds(
      (const __attribute__((address_space(1))) unsigned int*)g,
      (__attribute__((address_space(3))) unsigned int*)l, 16, 0, 0);
}

// ---------------- weight split: fp32 -> bf16 hi/lo (4 matrices) ----------------
struct WSplitArgs { const float* src[4]; short* hi[4]; short* lo[4]; };

__global__ __launch_bounds__(256)
void wsplit_kernel(WSplitArgs a) {
  const int seg = blockIdx.x >> 7;              // 4 segs x 128 blocks
  const size_t off = (size_t)(blockIdx.x & 127) * 2048 + (size_t)threadIdx.x * 8;
  const float* src = a.src[seg] + off;
  float4 v0 = *(const float4*)(src);
  float4 v1 = *(const float4*)(src + 4);
  short4v h0, l0, h1, l1;
  cvt4(v0, h0, l0); cvt4(v1, h1, l1);
  short8 vh = {h0[0],h0[1],h0[2],h0[3],h1[0],h1[1],h1[2],h1[3]};
  short8 vl = {l0[0],l0[1],l0[2],l0[3],l1[0],l1[1],l1[2],l1[3]};
  *(short8*)(a.hi[seg] + off) = vh;
  *(short8*)(a.lo[seg] + off) = vl;
}

// ======== k-split-2 bf16x3 MFMA GEMM, M-tile 16 (784 = 49*16, no bounds) ====
// Tile 16(M)x64(N), 512 thr = 2 k-groups x 4 waves, BK=32 per group.
// A fp32 (cvt on the fly), B pre-split bf16 via global_load_lds.
// wave w -> n-subtile w*16; per kt: 3 MFMAs. Optional gate epilogue.
struct GemmArgs {
  const float* X[3]; const short* Wh[3]; const short* Wl[3]; const float* bias[3];
  float* Cf[3]; short* Ch[3]; short* Cl[3]; const float* gate[3];
};

__global__ __launch_bounds__(512)
void mgemm(GemmArgs p, int N, int K) {
  const int z = blockIdx.z;
  const float* __restrict__ X  = p.X[z];
  const short* __restrict__ Wh = p.Wh[z];
  const short* __restrict__ Wl = p.Wl[z];

  __shared__ short smem[20480];                 // 40 KB
  short* const A_ = smem;                       // [g*2+buf][hl][16*32] 512 each
  short* const B_ = smem + 4096;                // [g*2+buf][hl][64*32] 2048 each
  float* const redC = (float*)smem;             // 4KB, aliases A after final barrier

  const int t = threadIdx.x;
  const int g = t >> 8;
  const int tt = t & 255;
  const int ln = t & 63, lm = ln & 15, quad = ln >> 4;
  const int w = (t >> 6) & 3;
  const int m0 = blockIdx.x * 16, n0 = blockIdx.y * 64;
  const int kb = g << 8;

  // A staging: 16 rows x 32 k fp32, 128 loader threads x float4
  const int aRow = (tt & 127) >> 3, aK = (tt & 7) << 2;
  const bool aload = tt < 128;
  const float* Ap = X + (size_t)(m0 + aRow) * K + kb + aK;
  const int aIdx = aRow * 32 + aK;
  // B staging: 64 rows x 32 k shorts, 8/thread via DMA (lane-linear tt*8)
  const int bRow = tt >> 2, bK = (tt & 3) << 3;
  const short* Bph = Wh + (size_t)(n0 + bRow) * K + kb + bK;
  const short* Bpl = Wl + (size_t)(n0 + bRow) * K + kb + bK;

  const int wn = w << 4;
  float4v acc = {0.f, 0.f, 0.f, 0.f};

  const int T = 8;
  float4 ra = aload ? *(const float4*)Ap : make_float4(0.f,0.f,0.f,0.f);
  gload_lds16(Bph, &B_[(((g << 1) + 0) * 2 + 0) * 2048 + tt * 8]);
  gload_lds16(Bpl, &B_[(((g << 1) + 0) * 2 + 1) * 2048 + tt * 8]);
  if (aload) {
    short4v ahi, alo; cvt4(ra, ahi, alo);
    *(short4v*)&A_[(((g << 1) + 0) * 2 + 0) * 512 + aIdx] = ahi;
    *(short4v*)&A_[(((g << 1) + 0) * 2 + 1) * 512 + aIdx] = alo;
  }

  for (int kt = 0; kt < T; ++kt) {
    const int buf = kt & 1;
    __syncthreads();                            // buf ready (DMA drained)
    if (kt + 1 < T) {
      if (aload) ra = *(const float4*)(Ap + (size_t)(kt + 1) * 32);
      const int nb = buf ^ 1;
      gload_lds16(Bph + (size_t)(kt + 1) * 32, &B_[(((g << 1) + nb) * 2 + 0) * 2048 + tt * 8]);
      gload_lds16(Bpl + (size_t)(kt + 1) * 32, &B_[(((g << 1) + nb) * 2 + 1) * 2048 + tt * 8]);
    }
    const short* Ab = &A_[((g << 1) + buf) * 2 * 512];
    const short* Bb = &B_[((g << 1) + buf) * 2 * 2048];
    short8 fah = *(const short8*)&Ab[0 * 512 + lm * 32 + (quad << 3)];
    short8 fal = *(const short8*)&Ab[1 * 512 + lm * 32 + (quad << 3)];
    short8 fbh = *(const short8*)&Bb[0 * 2048 + (wn + lm) * 32 + (quad << 3)];
    short8 fbl = *(const short8*)&Bb[1 * 2048 + (wn + lm) * 32 + (quad << 3)];
    acc = __builtin_amdgcn_mfma_f32_16x16x32_bf16(fah, fbh, acc, 0,0,0);
    acc = __builtin_amdgcn_mfma_f32_16x16x32_bf16(fah, fbl, acc, 0,0,0);
    acc = __builtin_amdgcn_mfma_f32_16x16x32_bf16(fal, fbh, acc, 0,0,0);
    if (kt + 1 < T) {
      const int nb = buf ^ 1;
      if (aload) {
        short4v ahi, alo; cvt4(ra, ahi, alo);
        *(short4v*)&A_[(((g << 1) + nb) * 2 + 0) * 512 + aIdx] = ahi;
        *(short4v*)&A_[(((g << 1) + nb) * 2 + 1) * 512 + aIdx] = alo;
      }
    }
  }

  __syncthreads();
  if (g == 1) *(float4v*)&redC[tt * 4] = acc;
  __syncthreads();
  if (g == 0) {
    const float* bias = p.bias[z];
    const float* gate = p.gate[z];
    float* Cf = p.Cf[z]; short* Ch = p.Ch[z]; short* Cl = p.Cl[z];
    const int n = n0 + wn + lm;
    const float bv = bias[n];
    #pragma unroll
    for (int r = 0; r < 4; ++r) {
      const int m = m0 + (quad << 2) + r;
      float c = acc[r] + redC[tt * 4 + r] + bv;
      if (gate) {
        const float qg = gate[(size_t)m * N + n];
        c = __fdividef(c, 1.f + __expf(-qg * c));   // sigmoid(qg*c)*c
      }
      if (Cf) Cf[(size_t)m * N + n] = c;
      if (Ch) {
        const short hi = f2b(c);
        Ch[(size_t)m * N + n] = hi;
        Cl[(size_t)m * N + n] = f2b(c - b2f(hi));
      }
    }
  }
}

// ======== fused attention: scores (MFMA) + softmax + gated PV, 512 thr ======
// One block per (q-tile 16, h, b); 8 waves. S and p never leave LDS.
__global__ __launch_bounds__(512)
void attn_fused(const short* __restrict__ qsh, const short* __restrict__ qsl,
                const short* __restrict__ ksh, const short* __restrict__ ksl,
                const float* __restrict__ qsg, const float* __restrict__ kpg,
                const float* __restrict__ vpg, const float* __restrict__ scg,
                float* __restrict__ img) {
  const int q0 = blockIdx.x * 16;
  const int h  = blockIdx.y;
  const int b  = blockIdx.z;
  const int t  = threadIdx.x;
  const int w = t >> 6, ln = t & 63;
  const int lm = ln & 15, quad = ln >> 4;
  const float L2E = 1.4426950408889634f;

  __shared__ float S[16][210];     // scores, then p (broadcast reads are free)
  __shared__ float R[8][16][64];   // pv k-group partials (32 KB)

  // ---- phase 1: S = q_sig . k_p^T (bf16x3 MFMA), waves stride nt by 8 ----
  const size_t abase = ((size_t)(b * NQ) + q0 + lm) * HD + h * DK + (quad << 3);
  short8 ah0 = *(const short8*)(qsh + abase);
  short8 ah1 = *(const short8*)(qsh + abase + 32);
  short8 al0 = *(const short8*)(qsl + abase);
  short8 al1 = *(const short8*)(qsl + abase + 32);

  for (int nt = w; nt < 13; nt += 8) {
    const size_t bbase = ((size_t)(b * NQ) + nt * 16 + lm) * HD + h * DK + (quad << 3);
    short8 bh0 = *(const short8*)(ksh + bbase);
    short8 bh1 = *(const short8*)(ksh + bbase + 32);
    short8 bl0 = *(const short8*)(ksl + bbase);
    short8 bl1 = *(const short8*)(ksl + bbase + 32);
    float4v acc = {0.f, 0.f, 0.f, 0.f};
    acc = __builtin_amdgcn_mfma_f32_16x16x32_bf16(ah0, bh0, acc, 0,0,0);
    acc = __builtin_amdgcn_mfma_f32_16x16x32_bf16(ah1, bh1, acc, 0,0,0);
    acc = __builtin_amdgcn_mfma_f32_16x16x32_bf16(ah0, bl0, acc, 0,0,0);
    acc = __builtin_amdgcn_mfma_f32_16x16x32_bf16(ah1, bl1, acc, 0,0,0);
    acc = __builtin_amdgcn_mfma_f32_16x16x32_bf16(al0, bh0, acc, 0,0,0);
    acc = __builtin_amdgcn_mfma_f32_16x16x32_bf16(al1, bh1, acc, 0,0,0);
    #pragma unroll
    for (int r = 0; r < 4; ++r)
      S[(quad << 2) + r][nt * 16 + lm] = acc[r];
  }
  __syncthreads();

  // ---- phase 2: softmax in place (wave w: rows 2w, 2w+1) ----
  for (int i = 0; i < 2; ++i) {
    const int rr = (w << 1) + i;
    const int q = q0 + rr;
    const bool qok = q < NQ;
    const float* srow = scg + ((size_t)h * NQ + (qok ? q : 0)) * NQ;
    float att[4];
    #pragma unroll
    for (int j = 0; j < 4; ++j) {
      const int c = ln + (j << 6);
      att[j] = -1e30f;
      if (c < NQ) att[j] = S[rr][c] * srow[c] * L2E;
    }
    float m = fmaxf(fmaxf(att[0], att[1]), fmaxf(att[2], att[3]));
    #pragma unroll
    for (int off = 32; off; off >>= 1) m = fmaxf(m, __shfl_xor(m, off, 64));
    float e[4], s = 0.f;
    #pragma unroll
    for (int j = 0; j < 4; ++j) { e[j] = fexp2(att[j] - m); s += e[j]; }
    #pragma unroll
    for (int off = 32; off; off >>= 1) s += __shfl_xor(s, off, 64);
    const float rinv = __fdividef(1.f, s);
    #pragma unroll
    for (int j = 0; j < 4; ++j) {
      const int c = ln + (j << 6);
      if (c < NQ) S[rr][c] = e[j] * rinv;
    }
  }
  __syncthreads();

  // ---- phase 3: gated PV. thread = (d = ln, kgroup = w of 8). ----
  const int d = ln;
  const int kg = w;
  const int kbeg = (kg * 49) >> 1;              // 196 split into 8 ranges
  const int kend = ((kg + 1) * 49) >> 1;
  const float LOG2E = 1.4426950408889634f;

  float nqs[16];
  #pragma unroll
  for (int qi = 0; qi < 16; ++qi) {
    const int row = min(b * NQ + q0 + qi, MROWS - 1);   // clamp tile overhang
    nqs[qi] = -qsg[(size_t)row * HD + h * DK + d] * LOG2E;
  }
  const float* kp = kpg + ((size_t)(b * NQ)) * HD + h * DK + d;
  const float* vp = vpg + ((size_t)(b * NQ)) * HD + h * DK + d;

  float acc[16];
  #pragma unroll
  for (int qi = 0; qi < 16; ++qi) acc[qi] = 0.f;

  for (int k = kbeg; k < kend; ++k) {
    const float kv = kp[(size_t)k * HD];
    const float vv = vp[(size_t)k * HD];
    #pragma unroll
    for (int qi = 0; qi < 16; ++qi) {
      const float e = fexp2(nqs[qi] * kv);          // e^(-qs*kv)
      const float g = vv * frcp(1.f + e);           // sigmoid(qs*kv)*vv
      acc[qi] += S[qi][k] * g;
    }
  }
  #pragma unroll
  for (int qi = 0; qi < 16; ++qi) R[kg][qi][d] = acc[qi];
  __syncthreads();

  #pragma unroll
  for (int j = 0; j < 2; ++j) {
    const int idx = t + (j << 9);
    const int qi = idx >> 6, dd = idx & 63;
    const int q = q0 + qi;
    if (q < NQ) {
      float s = 0.f;
      #pragma unroll
      for (int kk = 0; kk < 8; ++kk) s += R[kk][qi][dd];
      img[((size_t)(b * NQ) + q) * HD + h * DK + dd] = s;
    }
  }
}

extern "C" void kernel_launch(void* const* d_in, const int* in_sizes, int n_in,
                              void* d_out, int out_size, void* d_ws, size_t ws_size,
                              hipStream_t stream) {
  const float* queries = (const float*)d_in[0];
  const float* keys    = (const float*)d_in[1];
  const float* values  = (const float*)d_in[2];
  const float* Wq = (const float*)d_in[3];
  const float* bq = (const float*)d_in[4];
  const float* Wk = (const float*)d_in[5];
  const float* bk = (const float*)d_in[6];
  const float* Wv = (const float*)d_in[7];
  const float* bv = (const float*)d_in[8];
  const float* Wo = (const float*)d_in[9];
  const float* bo = (const float*)d_in[10];
  const float* scale = (const float*)d_in[11];

  char* base = (char*)d_ws;
  const size_t FB = sizeof(float);
  const size_t NELF  = (size_t)MROWS * HD;   // 401408
  const size_t NELPS = (size_t)MPAD * HD;    // 425984
  const size_t WEL   = (size_t)HD * HD;      // 262144

  size_t o = 0;
  float* q_sig = (float*)(base + o); o += NELF * FB;
  float* k_p   = (float*)(base + o); o += NELF * FB;
  float* v_p   = (float*)(base + o); o += NELF * FB;
  float* image = (float*)(base + o); o += NELF * FB;
  short* qsh = (short*)(base + o); o += NELPS * 2;
  short* qsl = (short*)(base + o); o += NELPS * 2;
  short* ksh = (short*)(base + o); o += NELPS * 2;
  short* ksl = (short*)(base + o); o += NELPS * 2;
  short* Wqh = (short*)(base + o); o += WEL * 2;
  short* Wql = (short*)(base + o); o += WEL * 2;
  short* Wkh = (short*)(base + o); o += WEL * 2;
  short* Wkl = (short*)(base + o); o += WEL * 2;
  short* Wvh = (short*)(base + o); o += WEL * 2;
  short* Wvl = (short*)(base + o); o += WEL * 2;
  short* Woh = (short*)(base + o); o += WEL * 2;
  short* Wol = (short*)(base + o); o += WEL * 2;

  // 0) split weights once
  WSplitArgs wa;
  wa.src[0] = Wq; wa.hi[0] = Wqh; wa.lo[0] = Wql;
  wa.src[1] = Wk; wa.hi[1] = Wkh; wa.lo[1] = Wkl;
  wa.src[2] = Wv; wa.hi[2] = Wvh; wa.lo[2] = Wvl;
  wa.src[3] = Wo; wa.hi[3] = Woh; wa.lo[3] = Wol;
  wsplit_kernel<<<512, 256, 0, stream>>>(wa);

  // 1) projections: z0 q_sig (fp32 + split), z1 k_p (fp32 + split), z2 v_p (fp32)
  GemmArgs gp;
  gp.X[0] = queries; gp.Wh[0] = Wqh; gp.Wl[0] = Wql; gp.bias[0] = bq;
  gp.Cf[0] = q_sig;  gp.Ch[0] = qsh; gp.Cl[0] = qsl; gp.gate[0] = nullptr;
  gp.X[1] = keys;    gp.Wh[1] = Wkh; gp.Wl[1] = Wkl; gp.bias[1] = bk;
  gp.Cf[1] = k_p;    gp.Ch[1] = ksh; gp.Cl[1] = ksl; gp.gate[1] = nullptr;
  gp.X[2] = values;  gp.Wh[2] = Wvh; gp.Wl[2] = Wvl; gp.bias[2] = bv;
  gp.Cf[2] = v_p;    gp.Ch[2] = nullptr; gp.Cl[2] = nullptr; gp.gate[2] = nullptr;
  mgemm<<<dim3(MROWS/16, HD/64, 3), 512, 0, stream>>>(gp, HD, HD);

  // 2) fused scores + softmax + gated PV -> image
  attn_fused<<<dim3(13, NH, BATCH), 512, 0, stream>>>(
      qsh, qsl, ksh, ksl, q_sig, k_p, v_p, scale, image);

  // 3) out = image @ Wo^T + bo, gated by q_sig
  GemmArgs go;
  go.X[0] = image; go.Wh[0] = Woh; go.Wl[0] = Wol; go.bias[0] = bo;
  go.Cf[0] = (float*)d_out; go.Ch[0] = nullptr; go.Cl[0] = nullptr; go.gate[0] = q_sig;
  for (int i = 1; i < 3; ++i) {
    go.X[i] = nullptr; go.Wh[i] = nullptr; go.Wl[i] = nullptr; go.bias[i] = nullptr;
    go.Cf[i] = nullptr; go.Ch[i] = nullptr; go.Cl[i] = nullptr; go.gate[i] = nullptr;
  }
  mgemm<<<dim3(MROWS/16, HD/64, 1), 512, 0, stream>>>(go, HD, HD);
}